// Round 1
// baseline (272.002 us; speedup 1.0000x reference)
//
#include <hip/hip_runtime.h>

#define N_NODES 4096
#define B_PTS   4096
#define SUPPORT_FACTOR 2.5f
#define EPSILON 1e-5f

// ---------------------------------------------------------------------------
// Kernel 1: dilation = SUPPORT_FACTOR * mean_i( sqrt( min_{j!=i} |n_i-n_j|^2 ) )
// One block per node i; threads stride over j; wave-min + LDS-min reduce;
// block leader atomicAdds its contribution to the mean (pre-scaled).
// ---------------------------------------------------------------------------
__global__ __launch_bounds__(256) void dilation_kernel(
        const float* __restrict__ nodes, float* __restrict__ dsum) {
    const int i = blockIdx.x;
    const float xi = nodes[2 * i];
    const float yi = nodes[2 * i + 1];

    float mind2 = 3.4e38f;
    for (int j = threadIdx.x; j < N_NODES; j += 256) {
        float dx = xi - nodes[2 * j];
        float dy = yi - nodes[2 * j + 1];
        float d2 = dx * dx + dy * dy;
        if (j != i) mind2 = fminf(mind2, d2);
    }
    // wave (64-lane) min reduction
    #pragma unroll
    for (int off = 32; off > 0; off >>= 1)
        mind2 = fminf(mind2, __shfl_down(mind2, off, 64));

    __shared__ float sw[4];
    const int wave = threadIdx.x >> 6;
    if ((threadIdx.x & 63) == 0) sw[wave] = mind2;
    __syncthreads();
    if (threadIdx.x == 0) {
        float m = fminf(fminf(sw[0], sw[1]), fminf(sw[2], sw[3]));
        atomicAdd(dsum, sqrtf(m) * (SUPPORT_FACTOR / (float)N_NODES));
    }
}

// ---------------------------------------------------------------------------
// Cubic spline weight (already masked to zero outside q>1)
// ---------------------------------------------------------------------------
__device__ __forceinline__ float cubic_w(float q) {
    // q <= 0.5 : 2/3 - 4q^2 + 4q^3  = 2/3 + q^2*(4q - 4)
    // q <= 1.0 : 4/3 - 4q + 4q^2 - (4/3)q^3 = 4/3 + q*(-4 + q*(4 - (4/3)q))
    if (q <= 0.5f) return 2.0f / 3.0f + q * q * (4.0f * q - 4.0f);
    if (q <= 1.0f) return 4.0f / 3.0f + q * (-4.0f + q * (4.0f - (4.0f / 3.0f) * q));
    return 0.0f;
}

// ---------------------------------------------------------------------------
// Kernel 2: one block per query point b.
//  - stage nodes (32 KB) into LDS
//  - pass 1: accumulate symmetric 3x3 moment matrix (6 entries)
//  - thread 0: analytic inverse with eps regularization -> LDS broadcast
//  - pass 2: write phi / phi_x / phi_y, stride-256 coalesced stores
// Output layout (concat of tuple, row-major [B, N]):
//   out[0*B*N + b*N + n] = phi,  out[1*B*N + ...] = phi_x,  out[2*B*N + ...] = phi_y
// ---------------------------------------------------------------------------
__global__ __launch_bounds__(256) void rkpm_kernel(
        const float* __restrict__ x, const float* __restrict__ nodes,
        const float* __restrict__ dsum, float* __restrict__ out) {
    __shared__ float2 snodes[N_NODES];   // 32 KB
    __shared__ float sred[4][6];
    __shared__ float sminv[6];

    const int b = blockIdx.x;
    const int tid = threadIdx.x;

    // stage nodes into LDS (coalesced float2 loads)
    const float2* nodes2 = (const float2*)nodes;
    for (int j = tid; j < N_NODES; j += 256) snodes[j] = nodes2[j];

    const float xb = x[2 * b];
    const float yb = x[2 * b + 1];
    const float inv_dil = 1.0f / (*dsum);
    __syncthreads();

    // ---- pass 1: moment matrix ----
    float m00 = 0.f, m01 = 0.f, m02 = 0.f, m11 = 0.f, m12 = 0.f, m22 = 0.f;
    for (int j = tid; j < N_NODES; j += 256) {
        float2 nd = snodes[j];
        float dx = xb - nd.x;
        float dy = yb - nd.y;
        float dist = sqrtf(dx * dx + dy * dy + 1e-10f);
        float w = cubic_w(dist * inv_dil);
        m00 += w;
        m01 += w * dx;
        m02 += w * dy;
        m11 += w * dx * dx;
        m12 += w * dx * dy;
        m22 += w * dy * dy;
    }
    #pragma unroll
    for (int off = 32; off > 0; off >>= 1) {
        m00 += __shfl_down(m00, off, 64);
        m01 += __shfl_down(m01, off, 64);
        m02 += __shfl_down(m02, off, 64);
        m11 += __shfl_down(m11, off, 64);
        m12 += __shfl_down(m12, off, 64);
        m22 += __shfl_down(m22, off, 64);
    }
    const int wave = tid >> 6;
    if ((tid & 63) == 0) {
        sred[wave][0] = m00; sred[wave][1] = m01; sred[wave][2] = m02;
        sred[wave][3] = m11; sred[wave][4] = m12; sred[wave][5] = m22;
    }
    __syncthreads();

    if (tid == 0) {
        float a = sred[0][0] + sred[1][0] + sred[2][0] + sred[3][0] + EPSILON; // m00
        float bb = sred[0][1] + sred[1][1] + sred[2][1] + sred[3][1];          // m01
        float c = sred[0][2] + sred[1][2] + sred[2][2] + sred[3][2];           // m02
        float d = sred[0][3] + sred[1][3] + sred[2][3] + sred[3][3] + EPSILON; // m11
        float e = sred[0][4] + sred[1][4] + sred[2][4] + sred[3][4];           // m12
        float f = sred[0][5] + sred[1][5] + sred[2][5] + sred[3][5] + EPSILON; // m22
        // symmetric 3x3 inverse via adjugate
        float c00 = d * f - e * e;
        float c01 = c * e - bb * f;
        float c02 = bb * e - c * d;
        float det = a * c00 + bb * c01 + c * c02;
        float idet = 1.0f / det;
        sminv[0] = c00 * idet;                  // i00
        sminv[1] = c01 * idet;                  // i01
        sminv[2] = c02 * idet;                  // i02
        sminv[3] = (a * f - c * c) * idet;      // i11
        sminv[4] = (bb * c - a * e) * idet;     // i12
        sminv[5] = (a * d - bb * bb) * idet;    // i22
    }
    __syncthreads();

    const float i00 = sminv[0], i01 = sminv[1], i02 = sminv[2];
    const float i11 = sminv[3], i12 = sminv[4], i22 = sminv[5];

    const size_t BN = (size_t)B_PTS * N_NODES;
    float* __restrict__ out_phi = out + (size_t)b * N_NODES;
    float* __restrict__ out_px  = out + BN + (size_t)b * N_NODES;
    float* __restrict__ out_py  = out + 2 * BN + (size_t)b * N_NODES;

    // ---- pass 2: write outputs (coalesced: lane i -> element i) ----
    for (int j = tid; j < N_NODES; j += 256) {
        float2 nd = snodes[j];
        float dx = xb - nd.x;
        float dy = yb - nd.y;
        float dist = sqrtf(dx * dx + dy * dy + 1e-10f);
        float w = cubic_w(dist * inv_dil);
        float wdx = w * dx;
        float wdy = w * dy;
        out_phi[j] = i00 * w + i01 * wdx + i02 * wdy;
        out_px[j]  = -(i01 * w + i11 * wdx + i12 * wdy);
        out_py[j]  = -(i02 * w + i12 * wdx + i22 * wdy);
    }
}

extern "C" void kernel_launch(void* const* d_in, const int* in_sizes, int n_in,
                              void* d_out, int out_size, void* d_ws, size_t ws_size,
                              hipStream_t stream) {
    const float* x     = (const float*)d_in[0];   // [4096, 2]
    const float* nodes = (const float*)d_in[1];   // [4096, 2]
    float* out = (float*)d_out;                   // 3 * 4096 * 4096 floats
    float* dsum = (float*)d_ws;                   // 4-byte accumulator

    // zero the dilation accumulator (async memset is graph-capturable)
    hipMemsetAsync(dsum, 0, sizeof(float), stream);

    dilation_kernel<<<N_NODES, 256, 0, stream>>>(nodes, dsum);
    rkpm_kernel<<<B_PTS, 256, 0, stream>>>(x, nodes, dsum, out);
}

// Round 2
// 216.813 us; speedup vs baseline: 1.2545x; 1.2545x over previous
//
#include <hip/hip_runtime.h>

#define N_NODES 4096
#define B_PTS   4096
#define SUPPORT_FACTOR 2.5f
#define EPSILON 1e-5f

// ---------------------------------------------------------------------------
// Kernel 1: per-node nearest-neighbor distance (no atomics).
// One block per node i; threads stride over j; wave-min + LDS-min reduce;
// thread 0 writes sqrt(min d2) to mind[i].
// ---------------------------------------------------------------------------
__global__ __launch_bounds__(256) void nearest_kernel(
        const float* __restrict__ nodes, float* __restrict__ mind) {
    const int i = blockIdx.x;
    const float xi = nodes[2 * i];
    const float yi = nodes[2 * i + 1];

    float mind2 = 3.4e38f;
    for (int j = threadIdx.x; j < N_NODES; j += 256) {
        float dx = xi - nodes[2 * j];
        float dy = yi - nodes[2 * j + 1];
        float d2 = dx * dx + dy * dy;
        if (j != i) mind2 = fminf(mind2, d2);
    }
    #pragma unroll
    for (int off = 32; off > 0; off >>= 1)
        mind2 = fminf(mind2, __shfl_down(mind2, off, 64));

    __shared__ float sw[4];
    const int wave = threadIdx.x >> 6;
    if ((threadIdx.x & 63) == 0) sw[wave] = mind2;
    __syncthreads();
    if (threadIdx.x == 0) {
        float m = fminf(fminf(sw[0], sw[1]), fminf(sw[2], sw[3]));
        mind[i] = sqrtf(m);
    }
}

// ---------------------------------------------------------------------------
// Kernel 2: single-block sum of mind[] -> dilation scalar. No atomics.
// ---------------------------------------------------------------------------
__global__ __launch_bounds__(256) void dil_reduce_kernel(
        const float* __restrict__ mind, float* __restrict__ dsum) {
    float s = 0.f;
    const float4* m4 = (const float4*)mind;
    for (int k = threadIdx.x; k < N_NODES / 4; k += 256) {
        float4 v = m4[k];
        s += (v.x + v.y) + (v.z + v.w);
    }
    #pragma unroll
    for (int off = 32; off > 0; off >>= 1)
        s += __shfl_down(s, off, 64);
    __shared__ float sw[4];
    const int wave = threadIdx.x >> 6;
    if ((threadIdx.x & 63) == 0) sw[wave] = s;
    __syncthreads();
    if (threadIdx.x == 0)
        *dsum = (sw[0] + sw[1] + sw[2] + sw[3]) * (SUPPORT_FACTOR / (float)N_NODES);
}

// ---------------------------------------------------------------------------
// Cubic spline weight (zero outside q > 1)
// ---------------------------------------------------------------------------
__device__ __forceinline__ float cubic_w(float q) {
    if (q <= 0.5f) return 2.0f / 3.0f + q * q * (4.0f * q - 4.0f);
    if (q <= 1.0f) return 4.0f / 3.0f + q * (-4.0f + q * (4.0f - (4.0f / 3.0f) * q));
    return 0.0f;
}

__device__ __forceinline__ void node_eval(float xb, float yb, float nx, float ny,
                                          float inv_dil, float& w, float& dx, float& dy) {
    dx = xb - nx;
    dy = yb - ny;
    float dist = sqrtf(dx * dx + dy * dy + 1e-10f);
    w = cubic_w(dist * inv_dil);
}

// ---------------------------------------------------------------------------
// Kernel 3: one block per query point b.
//  - stage nodes into LDS as SoA (sx, sy) for 16B-stride ds_read_b128
//  - pass 1: symmetric 3x3 moment matrix, 4 nodes/thread/iter
//  - thread 0: analytic adjugate inverse with eps regularization
//  - pass 2: float4 stores of phi / phi_x / phi_y (16 B/lane, fully coalesced)
// ---------------------------------------------------------------------------
__global__ __launch_bounds__(256) void rkpm_kernel(
        const float* __restrict__ x, const float* __restrict__ nodes,
        const float* __restrict__ dsum, float* __restrict__ out) {
    __shared__ float sx[N_NODES];   // 16 KB
    __shared__ float sy[N_NODES];   // 16 KB
    __shared__ float sred[4][6];
    __shared__ float sminv[6];

    const int b = blockIdx.x;
    const int tid = threadIdx.x;

    const float2* nodes2 = (const float2*)nodes;
    for (int j = tid; j < N_NODES; j += 256) {
        float2 nd = nodes2[j];
        sx[j] = nd.x;
        sy[j] = nd.y;
    }

    const float xb = x[2 * b];
    const float yb = x[2 * b + 1];
    const float inv_dil = 1.0f / (*dsum);
    __syncthreads();

    const float4* sx4 = (const float4*)sx;
    const float4* sy4 = (const float4*)sy;

    // ---- pass 1: moment matrix (4 nodes per thread per iteration) ----
    float m00 = 0.f, m01 = 0.f, m02 = 0.f, m11 = 0.f, m12 = 0.f, m22 = 0.f;
    for (int k = 0; k < N_NODES / 4; k += 256) {
        const int idx = k + tid;
        float4 xs = sx4[idx];
        float4 ys = sy4[idx];
        float w, dx, dy;
        #pragma unroll
        for (int c = 0; c < 4; ++c) {
            float nx = (c == 0) ? xs.x : (c == 1) ? xs.y : (c == 2) ? xs.z : xs.w;
            float ny = (c == 0) ? ys.x : (c == 1) ? ys.y : (c == 2) ? ys.z : ys.w;
            node_eval(xb, yb, nx, ny, inv_dil, w, dx, dy);
            m00 += w;
            m01 += w * dx;
            m02 += w * dy;
            m11 += w * dx * dx;
            m12 += w * dx * dy;
            m22 += w * dy * dy;
        }
    }
    #pragma unroll
    for (int off = 32; off > 0; off >>= 1) {
        m00 += __shfl_down(m00, off, 64);
        m01 += __shfl_down(m01, off, 64);
        m02 += __shfl_down(m02, off, 64);
        m11 += __shfl_down(m11, off, 64);
        m12 += __shfl_down(m12, off, 64);
        m22 += __shfl_down(m22, off, 64);
    }
    const int wave = tid >> 6;
    if ((tid & 63) == 0) {
        sred[wave][0] = m00; sred[wave][1] = m01; sred[wave][2] = m02;
        sred[wave][3] = m11; sred[wave][4] = m12; sred[wave][5] = m22;
    }
    __syncthreads();

    if (tid == 0) {
        float a  = sred[0][0] + sred[1][0] + sred[2][0] + sred[3][0] + EPSILON; // m00
        float bb = sred[0][1] + sred[1][1] + sred[2][1] + sred[3][1];           // m01
        float c  = sred[0][2] + sred[1][2] + sred[2][2] + sred[3][2];           // m02
        float d  = sred[0][3] + sred[1][3] + sred[2][3] + sred[3][3] + EPSILON; // m11
        float e  = sred[0][4] + sred[1][4] + sred[2][4] + sred[3][4];           // m12
        float f  = sred[0][5] + sred[1][5] + sred[2][5] + sred[3][5] + EPSILON; // m22
        float c00 = d * f - e * e;
        float c01 = c * e - bb * f;
        float c02 = bb * e - c * d;
        float det = a * c00 + bb * c01 + c * c02;
        float idet = 1.0f / det;
        sminv[0] = c00 * idet;
        sminv[1] = c01 * idet;
        sminv[2] = c02 * idet;
        sminv[3] = (a * f - c * c) * idet;
        sminv[4] = (bb * c - a * e) * idet;
        sminv[5] = (a * d - bb * bb) * idet;
    }
    __syncthreads();

    const float i00 = sminv[0], i01 = sminv[1], i02 = sminv[2];
    const float i11 = sminv[3], i12 = sminv[4], i22 = sminv[5];

    const size_t BN = (size_t)B_PTS * N_NODES;
    float4* __restrict__ out_phi = (float4*)(out + (size_t)b * N_NODES);
    float4* __restrict__ out_px  = (float4*)(out + BN + (size_t)b * N_NODES);
    float4* __restrict__ out_py  = (float4*)(out + 2 * BN + (size_t)b * N_NODES);

    // ---- pass 2: float4 stores (lane i -> 16B-contiguous) ----
    for (int k = 0; k < N_NODES / 4; k += 256) {
        const int idx = k + tid;
        float4 xs = sx4[idx];
        float4 ys = sy4[idx];
        float4 ph, px, py;
        float w, dx, dy;

        node_eval(xb, yb, xs.x, ys.x, inv_dil, w, dx, dy);
        ph.x = i00 * w + i01 * (w * dx) + i02 * (w * dy);
        px.x = -(i01 * w + i11 * (w * dx) + i12 * (w * dy));
        py.x = -(i02 * w + i12 * (w * dx) + i22 * (w * dy));

        node_eval(xb, yb, xs.y, ys.y, inv_dil, w, dx, dy);
        ph.y = i00 * w + i01 * (w * dx) + i02 * (w * dy);
        px.y = -(i01 * w + i11 * (w * dx) + i12 * (w * dy));
        py.y = -(i02 * w + i12 * (w * dx) + i22 * (w * dy));

        node_eval(xb, yb, xs.z, ys.z, inv_dil, w, dx, dy);
        ph.z = i00 * w + i01 * (w * dx) + i02 * (w * dy);
        px.z = -(i01 * w + i11 * (w * dx) + i12 * (w * dy));
        py.z = -(i02 * w + i12 * (w * dx) + i22 * (w * dy));

        node_eval(xb, yb, xs.w, ys.w, inv_dil, w, dx, dy);
        ph.w = i00 * w + i01 * (w * dx) + i02 * (w * dy);
        px.w = -(i01 * w + i11 * (w * dx) + i12 * (w * dy));
        py.w = -(i02 * w + i12 * (w * dx) + i22 * (w * dy));

        out_phi[idx] = ph;
        out_px[idx]  = px;
        out_py[idx]  = py;
    }
}

extern "C" void kernel_launch(void* const* d_in, const int* in_sizes, int n_in,
                              void* d_out, int out_size, void* d_ws, size_t ws_size,
                              hipStream_t stream) {
    const float* x     = (const float*)d_in[0];   // [4096, 2]
    const float* nodes = (const float*)d_in[1];   // [4096, 2]
    float* out  = (float*)d_out;                  // 3 * 4096 * 4096 floats
    float* mind = (float*)d_ws;                   // [4096] nearest distances
    float* dsum = mind + N_NODES;                 // 1 float (dilation)

    nearest_kernel<<<N_NODES, 256, 0, stream>>>(nodes, mind);
    dil_reduce_kernel<<<1, 256, 0, stream>>>(mind, dsum);
    rkpm_kernel<<<B_PTS, 256, 0, stream>>>(x, nodes, dsum, out);
}

// Round 3
// 212.356 us; speedup vs baseline: 1.2809x; 1.0210x over previous
//
#include <hip/hip_runtime.h>

#define N_NODES 4096
#define B_PTS   4096
#define SUPPORT_FACTOR 2.5f
#define EPSILON 1e-5f

// ---------------------------------------------------------------------------
// Kernel 1: per-node nearest-neighbor distance (no atomics).
// One block per node i; threads stride over node pairs via float4 loads;
// wave-min + LDS-min reduce; thread 0 writes sqrt(min d2) to mind[i].
// ---------------------------------------------------------------------------
__global__ __launch_bounds__(256) void nearest_kernel(
        const float* __restrict__ nodes, float* __restrict__ mind) {
    const int i = blockIdx.x;
    const float xi = nodes[2 * i];
    const float yi = nodes[2 * i + 1];

    const float4* nodes4 = (const float4*)nodes;  // 2 nodes per float4
    float mind2 = 3.4e38f;
    for (int k = threadIdx.x; k < N_NODES / 2; k += 256) {
        float4 v = nodes4[k];                     // nodes 2k and 2k+1
        float dx0 = xi - v.x, dy0 = yi - v.y;
        float dx1 = xi - v.z, dy1 = yi - v.w;
        float d20 = dx0 * dx0 + dy0 * dy0;
        float d21 = dx1 * dx1 + dy1 * dy1;
        if (2 * k != i)     mind2 = fminf(mind2, d20);
        if (2 * k + 1 != i) mind2 = fminf(mind2, d21);
    }
    #pragma unroll
    for (int off = 32; off > 0; off >>= 1)
        mind2 = fminf(mind2, __shfl_down(mind2, off, 64));

    __shared__ float sw[4];
    const int wave = threadIdx.x >> 6;
    if ((threadIdx.x & 63) == 0) sw[wave] = mind2;
    __syncthreads();
    if (threadIdx.x == 0) {
        float m = fminf(fminf(sw[0], sw[1]), fminf(sw[2], sw[3]));
        mind[i] = sqrtf(m);
    }
}

// ---------------------------------------------------------------------------
// Kernel 2: single-block sum of mind[] -> dilation scalar. No atomics.
// ---------------------------------------------------------------------------
__global__ __launch_bounds__(256) void dil_reduce_kernel(
        const float* __restrict__ mind, float* __restrict__ dsum) {
    float s = 0.f;
    const float4* m4 = (const float4*)mind;
    for (int k = threadIdx.x; k < N_NODES / 4; k += 256) {
        float4 v = m4[k];
        s += (v.x + v.y) + (v.z + v.w);
    }
    #pragma unroll
    for (int off = 32; off > 0; off >>= 1)
        s += __shfl_down(s, off, 64);
    __shared__ float sw[4];
    const int wave = threadIdx.x >> 6;
    if ((threadIdx.x & 63) == 0) sw[wave] = s;
    __syncthreads();
    if (threadIdx.x == 0)
        *dsum = (sw[0] + sw[1] + sw[2] + sw[3]) * (SUPPORT_FACTOR / (float)N_NODES);
}

// ---------------------------------------------------------------------------
// Cubic spline weight (zero outside q > 1)
// ---------------------------------------------------------------------------
__device__ __forceinline__ float cubic_w(float q) {
    if (q <= 0.5f) return 2.0f / 3.0f + q * q * (4.0f * q - 4.0f);
    if (q <= 1.0f) return 4.0f / 3.0f + q * (-4.0f + q * (4.0f - (4.0f / 3.0f) * q));
    return 0.0f;
}

// ---------------------------------------------------------------------------
// Kernel 3: one block per query point b.
//  - stage nodes into LDS as SoA (sx, sy)
//  - pass 1: symmetric 3x3 moment matrix; w for all 16 nodes/thread cached in
//    registers (no recompute of sqrt/spline in pass 2)
//  - thread 0: analytic adjugate inverse, eps regularization; negated rows
//    precomputed so the epilogue is pure FMA
//  - pass 2: factored epilogue phi = w*(i00 + i01*dx + i02*dy), float4 stores
// ---------------------------------------------------------------------------
__global__ __launch_bounds__(256) void rkpm_kernel(
        const float* __restrict__ x, const float* __restrict__ nodes,
        const float* __restrict__ dsum, float* __restrict__ out) {
    __shared__ float sx[N_NODES];   // 16 KB
    __shared__ float sy[N_NODES];   // 16 KB
    __shared__ float sred[4][6];
    __shared__ float sminv[9];      // i00,i01,i02, n01,n11,n12, n02,n12,n22

    const int b = blockIdx.x;
    const int tid = threadIdx.x;

    const float2* nodes2 = (const float2*)nodes;
    for (int j = tid; j < N_NODES; j += 256) {
        float2 nd = nodes2[j];
        sx[j] = nd.x;
        sy[j] = nd.y;
    }

    const float2 xq = ((const float2*)x)[b];
    const float xb = xq.x;
    const float yb = xq.y;
    const float inv_dil = 1.0f / (*dsum);
    __syncthreads();

    const float4* sx4 = (const float4*)sx;
    const float4* sy4 = (const float4*)sy;

    // ---- pass 1: moment matrix; cache w in registers ----
    float wreg[16];
    float m00 = 0.f, m01 = 0.f, m02 = 0.f, m11 = 0.f, m12 = 0.f, m22 = 0.f;
    #pragma unroll
    for (int kk = 0; kk < 4; ++kk) {
        const int idx = kk * 256 + tid;
        float4 xs = sx4[idx];
        float4 ys = sy4[idx];
        #pragma unroll
        for (int c = 0; c < 4; ++c) {
            float nx = (c == 0) ? xs.x : (c == 1) ? xs.y : (c == 2) ? xs.z : xs.w;
            float ny = (c == 0) ? ys.x : (c == 1) ? ys.y : (c == 2) ? ys.z : ys.w;
            float dx = xb - nx;
            float dy = yb - ny;
            float dist = sqrtf(dx * dx + dy * dy + 1e-10f);
            float w = cubic_w(dist * inv_dil);
            wreg[kk * 4 + c] = w;
            m00 += w;
            m01 += w * dx;
            m02 += w * dy;
            m11 += w * dx * dx;
            m12 += w * dx * dy;
            m22 += w * dy * dy;
        }
    }
    #pragma unroll
    for (int off = 32; off > 0; off >>= 1) {
        m00 += __shfl_down(m00, off, 64);
        m01 += __shfl_down(m01, off, 64);
        m02 += __shfl_down(m02, off, 64);
        m11 += __shfl_down(m11, off, 64);
        m12 += __shfl_down(m12, off, 64);
        m22 += __shfl_down(m22, off, 64);
    }
    const int wave = tid >> 6;
    if ((tid & 63) == 0) {
        sred[wave][0] = m00; sred[wave][1] = m01; sred[wave][2] = m02;
        sred[wave][3] = m11; sred[wave][4] = m12; sred[wave][5] = m22;
    }
    __syncthreads();

    if (tid == 0) {
        float a  = sred[0][0] + sred[1][0] + sred[2][0] + sred[3][0] + EPSILON; // m00
        float bb = sred[0][1] + sred[1][1] + sred[2][1] + sred[3][1];           // m01
        float c  = sred[0][2] + sred[1][2] + sred[2][2] + sred[3][2];           // m02
        float d  = sred[0][3] + sred[1][3] + sred[2][3] + sred[3][3] + EPSILON; // m11
        float e  = sred[0][4] + sred[1][4] + sred[2][4] + sred[3][4];           // m12
        float f  = sred[0][5] + sred[1][5] + sred[2][5] + sred[3][5] + EPSILON; // m22
        float c00 = d * f - e * e;
        float c01 = c * e - bb * f;
        float c02 = bb * e - c * d;
        float det = a * c00 + bb * c01 + c * c02;
        float idet = 1.0f / det;
        float i00 = c00 * idet;
        float i01 = c01 * idet;
        float i02 = c02 * idet;
        float i11 = (a * f - c * c) * idet;
        float i12 = (bb * c - a * e) * idet;
        float i22 = (a * d - bb * bb) * idet;
        sminv[0] = i00;  sminv[1] = i01;  sminv[2] = i02;   // phi row
        sminv[3] = -i01; sminv[4] = -i11; sminv[5] = -i12;  // phi_x row (negated)
        sminv[6] = -i02; sminv[7] = -i12; sminv[8] = -i22;  // phi_y row (negated)
    }
    __syncthreads();

    const float i00 = sminv[0], i01 = sminv[1], i02 = sminv[2];
    const float n01 = sminv[3], n11 = sminv[4], n12 = sminv[5];
    const float n02 = sminv[6], n12b = sminv[7], n22 = sminv[8];

    const size_t BN = (size_t)B_PTS * N_NODES;
    float4* __restrict__ out_phi = (float4*)(out + (size_t)b * N_NODES);
    float4* __restrict__ out_px  = (float4*)(out + BN + (size_t)b * N_NODES);
    float4* __restrict__ out_py  = (float4*)(out + 2 * BN + (size_t)b * N_NODES);

    // ---- pass 2: factored epilogue, float4 stores ----
    #pragma unroll
    for (int kk = 0; kk < 4; ++kk) {
        const int idx = kk * 256 + tid;
        float4 xs = sx4[idx];
        float4 ys = sy4[idx];
        float4 ph, px, py;
        #pragma unroll
        for (int c = 0; c < 4; ++c) {
            float nx = (c == 0) ? xs.x : (c == 1) ? xs.y : (c == 2) ? xs.z : xs.w;
            float ny = (c == 0) ? ys.x : (c == 1) ? ys.y : (c == 2) ? ys.z : ys.w;
            float dx = xb - nx;
            float dy = yb - ny;
            float w = wreg[kk * 4 + c];
            float vph = w * (i00 + i01 * dx + i02 * dy);
            float vpx = w * (n01 + n11 * dx + n12 * dy);
            float vpy = w * (n02 + n12b * dx + n22 * dy);
            if (c == 0) { ph.x = vph; px.x = vpx; py.x = vpy; }
            else if (c == 1) { ph.y = vph; px.y = vpx; py.y = vpy; }
            else if (c == 2) { ph.z = vph; px.z = vpx; py.z = vpy; }
            else { ph.w = vph; px.w = vpx; py.w = vpy; }
        }
        out_phi[idx] = ph;
        out_px[idx]  = px;
        out_py[idx]  = py;
    }
}

extern "C" void kernel_launch(void* const* d_in, const int* in_sizes, int n_in,
                              void* d_out, int out_size, void* d_ws, size_t ws_size,
                              hipStream_t stream) {
    const float* x     = (const float*)d_in[0];   // [4096, 2]
    const float* nodes = (const float*)d_in[1];   // [4096, 2]
    float* out  = (float*)d_out;                  // 3 * 4096 * 4096 floats
    float* mind = (float*)d_ws;                   // [4096] nearest distances
    float* dsum = mind + N_NODES;                 // 1 float (dilation)

    nearest_kernel<<<N_NODES, 256, 0, stream>>>(nodes, mind);
    dil_reduce_kernel<<<1, 256, 0, stream>>>(mind, dsum);
    rkpm_kernel<<<B_PTS, 256, 0, stream>>>(x, nodes, dsum, out);
}

// Round 4
// 209.065 us; speedup vs baseline: 1.3010x; 1.0157x over previous
//
#include <hip/hip_runtime.h>

#define N_NODES 4096
#define B_PTS   4096
#define SUPPORT_FACTOR 2.5f
#define EPSILON 1e-5f

// ---------------------------------------------------------------------------
// Kernel 1: per-node nearest-neighbor distance (no atomics).
// One block per node i; float4 loads (2 nodes each); wave+LDS min reduce.
// ---------------------------------------------------------------------------
__global__ __launch_bounds__(256) void nearest_kernel(
        const float* __restrict__ nodes, float* __restrict__ mind) {
    const int i = blockIdx.x;
    const float xi = nodes[2 * i];
    const float yi = nodes[2 * i + 1];

    const float4* nodes4 = (const float4*)nodes;  // 2 nodes per float4
    float mind2 = 3.4e38f;
    for (int k = threadIdx.x; k < N_NODES / 2; k += 256) {
        float4 v = nodes4[k];
        float dx0 = xi - v.x, dy0 = yi - v.y;
        float dx1 = xi - v.z, dy1 = yi - v.w;
        float d20 = dx0 * dx0 + dy0 * dy0;
        float d21 = dx1 * dx1 + dy1 * dy1;
        if (2 * k != i)     mind2 = fminf(mind2, d20);
        if (2 * k + 1 != i) mind2 = fminf(mind2, d21);
    }
    #pragma unroll
    for (int off = 32; off > 0; off >>= 1)
        mind2 = fminf(mind2, __shfl_down(mind2, off, 64));

    __shared__ float sw[4];
    const int wave = threadIdx.x >> 6;
    if ((threadIdx.x & 63) == 0) sw[wave] = mind2;
    __syncthreads();
    if (threadIdx.x == 0) {
        float m = fminf(fminf(sw[0], sw[1]), fminf(sw[2], sw[3]));
        mind[i] = sqrtf(m);
    }
}

// ---------------------------------------------------------------------------
// Cubic spline weight (zero outside q > 1)
// ---------------------------------------------------------------------------
__device__ __forceinline__ float cubic_w(float q) {
    if (q <= 0.5f) return 2.0f / 3.0f + q * q * (4.0f * q - 4.0f);
    if (q <= 1.0f) return 4.0f / 3.0f + q * (-4.0f + q * (4.0f - (4.0f / 3.0f) * q));
    return 0.0f;
}

// ---------------------------------------------------------------------------
// Kernel 2 (fused): one block per query point b.
//  Phase 0: block-reduces mind[] -> dilation (redundant per block; ~300 cyc,
//           cheaper than a separate 1-block kernel + 2 launch gaps)
//  Phase 1: nodes read ONCE from global (2x float4/thread/iter, coalesced,
//           L2-resident); w/dx/dy cached in 48 VGPRs; moment accumulate
//  Phase 2: thread 0 analytic adjugate inverse (negated deriv rows)
//  Phase 3: pure-register epilogue, float4 coalesced stores
//  Index map: iter kk, thread t owns nodes [kk*1024+4t .. +3] -> store float4
//  index kk*256+t (consecutive threads -> consecutive 16B). No node LDS.
// ---------------------------------------------------------------------------
__global__ __launch_bounds__(256, 4) void rkpm_kernel(
        const float* __restrict__ x, const float* __restrict__ nodes,
        const float* __restrict__ mind, float* __restrict__ out) {
    __shared__ float sred[4][6];
    __shared__ float sbc[10];   // [0]=inv_dil, [1..9]=inverse rows (phi, -dx, -dy)

    const int b = blockIdx.x;
    const int tid = threadIdx.x;
    const int wave = tid >> 6;
    const int lane = tid & 63;

    // ---- phase 0: dilation from mind[] ----
    const float4* m4 = (const float4*)mind;
    float s = 0.f;
    #pragma unroll
    for (int k = 0; k < 4; ++k) {
        float4 v = m4[k * 256 + tid];
        s += (v.x + v.y) + (v.z + v.w);
    }
    #pragma unroll
    for (int off = 32; off > 0; off >>= 1)
        s += __shfl_down(s, off, 64);
    if (lane == 0) sred[wave][0] = s;
    __syncthreads();
    if (tid == 0) {
        float dil = (sred[0][0] + sred[1][0] + sred[2][0] + sred[3][0]) *
                    (SUPPORT_FACTOR / (float)N_NODES);
        sbc[0] = 1.0f / dil;
    }
    __syncthreads();
    const float inv_dil = sbc[0];

    const float2 xq = ((const float2*)x)[b];
    const float xb = xq.x, yb = xq.y;

    // ---- phase 1: moment matrix; cache w, dx, dy ----
    const float4* nodes4 = (const float4*)nodes;   // 2 nodes per float4
    float wr[16], dxr[16], dyr[16];
    float m00 = 0.f, m01 = 0.f, m02 = 0.f, m11 = 0.f, m12 = 0.f, m22 = 0.f;
    #pragma unroll
    for (int kk = 0; kk < 4; ++kk) {
        float4 va = nodes4[kk * 512 + 2 * tid];      // nodes 4t, 4t+1 (of chunk)
        float4 vb = nodes4[kk * 512 + 2 * tid + 1];  // nodes 4t+2, 4t+3
        #pragma unroll
        for (int c = 0; c < 4; ++c) {
            float nx = (c == 0) ? va.x : (c == 1) ? va.z : (c == 2) ? vb.x : vb.z;
            float ny = (c == 0) ? va.y : (c == 1) ? va.w : (c == 2) ? vb.y : vb.w;
            float dx = xb - nx;
            float dy = yb - ny;
            float dist = sqrtf(dx * dx + dy * dy + 1e-10f);
            float w = cubic_w(dist * inv_dil);
            const int r = kk * 4 + c;
            wr[r] = w; dxr[r] = dx; dyr[r] = dy;
            m00 += w;
            m01 += w * dx;
            m02 += w * dy;
            m11 += w * dx * dx;
            m12 += w * dx * dy;
            m22 += w * dy * dy;
        }
    }
    #pragma unroll
    for (int off = 32; off > 0; off >>= 1) {
        m00 += __shfl_down(m00, off, 64);
        m01 += __shfl_down(m01, off, 64);
        m02 += __shfl_down(m02, off, 64);
        m11 += __shfl_down(m11, off, 64);
        m12 += __shfl_down(m12, off, 64);
        m22 += __shfl_down(m22, off, 64);
    }
    if (lane == 0) {
        sred[wave][0] = m00; sred[wave][1] = m01; sred[wave][2] = m02;
        sred[wave][3] = m11; sred[wave][4] = m12; sred[wave][5] = m22;
    }
    __syncthreads();

    // ---- phase 2: analytic symmetric 3x3 inverse ----
    if (tid == 0) {
        float a  = sred[0][0] + sred[1][0] + sred[2][0] + sred[3][0] + EPSILON;
        float bb = sred[0][1] + sred[1][1] + sred[2][1] + sred[3][1];
        float c  = sred[0][2] + sred[1][2] + sred[2][2] + sred[3][2];
        float d  = sred[0][3] + sred[1][3] + sred[2][3] + sred[3][3] + EPSILON;
        float e  = sred[0][4] + sred[1][4] + sred[2][4] + sred[3][4];
        float f  = sred[0][5] + sred[1][5] + sred[2][5] + sred[3][5] + EPSILON;
        float c00 = d * f - e * e;
        float c01 = c * e - bb * f;
        float c02 = bb * e - c * d;
        float det = a * c00 + bb * c01 + c * c02;
        float idet = 1.0f / det;
        float i00 = c00 * idet;
        float i01 = c01 * idet;
        float i02 = c02 * idet;
        float i11 = (a * f - c * c) * idet;
        float i12 = (bb * c - a * e) * idet;
        float i22 = (a * d - bb * bb) * idet;
        sbc[1] = i00;  sbc[2] = i01;  sbc[3] = i02;   // phi row
        sbc[4] = -i01; sbc[5] = -i11; sbc[6] = -i12;  // phi_x row (negated)
        sbc[7] = -i02; sbc[8] = -i12; sbc[9] = -i22;  // phi_y row (negated)
    }
    __syncthreads();

    const float i00 = sbc[1], i01 = sbc[2], i02 = sbc[3];
    const float n01 = sbc[4], n11 = sbc[5], n12 = sbc[6];
    const float n02 = sbc[7], n12b = sbc[8], n22 = sbc[9];

    const size_t BN = (size_t)B_PTS * N_NODES;
    float4* __restrict__ out_phi = (float4*)(out + (size_t)b * N_NODES);
    float4* __restrict__ out_px  = (float4*)(out + BN + (size_t)b * N_NODES);
    float4* __restrict__ out_py  = (float4*)(out + 2 * BN + (size_t)b * N_NODES);

    // ---- phase 3: pure-register epilogue, float4 stores ----
    #pragma unroll
    for (int kk = 0; kk < 4; ++kk) {
        float4 ph, px, py;
        #pragma unroll
        for (int c = 0; c < 4; ++c) {
            const int r = kk * 4 + c;
            float w = wr[r], dx = dxr[r], dy = dyr[r];
            float vph = w * (i00 + i01 * dx + i02 * dy);
            float vpx = w * (n01 + n11 * dx + n12 * dy);
            float vpy = w * (n02 + n12b * dx + n22 * dy);
            if (c == 0)      { ph.x = vph; px.x = vpx; py.x = vpy; }
            else if (c == 1) { ph.y = vph; px.y = vpx; py.y = vpy; }
            else if (c == 2) { ph.z = vph; px.z = vpx; py.z = vpy; }
            else             { ph.w = vph; px.w = vpx; py.w = vpy; }
        }
        const int idx = kk * 256 + tid;
        out_phi[idx] = ph;
        out_px[idx]  = px;
        out_py[idx]  = py;
    }
}

extern "C" void kernel_launch(void* const* d_in, const int* in_sizes, int n_in,
                              void* d_out, int out_size, void* d_ws, size_t ws_size,
                              hipStream_t stream) {
    const float* x     = (const float*)d_in[0];   // [4096, 2]
    const float* nodes = (const float*)d_in[1];   // [4096, 2]
    float* out  = (float*)d_out;                  // 3 * 4096 * 4096 floats
    float* mind = (float*)d_ws;                   // [4096] nearest distances

    nearest_kernel<<<N_NODES, 256, 0, stream>>>(nodes, mind);
    rkpm_kernel<<<B_PTS, 256, 0, stream>>>(x, nodes, mind, out);
}